// Round 1
// baseline (945.305 us; speedup 1.0000x reference)
//
#include <hip/hip_runtime.h>
#include <hip/hip_bf16.h>
#include <cstdint>

// Problem constants (from reference): x (4,2048,4096) f32, W (16384,4096) f32
// out (4,2048,16384) f32.  M=8192, K=4096, N=16384.
constexpr int Mx = 8192;
constexpr int Kx = 4096;
constexpr int Nx = 16384;
constexpr long W_ELEMS = (long)Nx * Kx;      // 67108864
constexpr long X_ELEMS = (long)Mx * Kx;      // 33554432

typedef int v4i __attribute__((ext_vector_type(4)));

#define GLOBAL_AS(p) ((const __attribute__((address_space(1))) void*)(p))
#define LDS_AS(p)    ((__attribute__((address_space(3))) void*)(p))

// ---------------- Pass 1: sum |W| (deterministic two-level tree) ----------------
__global__ __launch_bounds__(256) void absum_kernel(const float4* __restrict__ W4,
                                                    double* __restrict__ partials) {
    int t = threadIdx.x;
    long base = (long)blockIdx.x * 8192;   // 2048 blocks * 8192 float4 = 16777216
    double s = 0.0;
#pragma unroll 4
    for (int i = 0; i < 32; ++i) {
        float4 v = W4[base + (long)i * 256 + t];
        s += (double)fabsf(v.x) + (double)fabsf(v.y) +
             (double)fabsf(v.z) + (double)fabsf(v.w);
    }
    __shared__ double sm[256];
    sm[t] = s;
    __syncthreads();
    for (int off = 128; off > 0; off >>= 1) {
        if (t < off) sm[t] += sm[t + off];
        __syncthreads();
    }
    if (t == 0) partials[blockIdx.x] = sm[0];
}

__global__ __launch_bounds__(256) void finalize_kernel(const double* __restrict__ partials,
                                                       float* __restrict__ thr) {
    int t = threadIdx.x;
    double s = 0.0;
#pragma unroll
    for (int i = 0; i < 8; ++i) s += partials[(long)i * 256 + t];
    __shared__ double sm[256];
    sm[t] = s;
    __syncthreads();
    for (int off = 128; off > 0; off >>= 1) {
        if (t < off) sm[t] += sm[t + off];
        __syncthreads();
    }
    if (t == 0) {
        double gamma = sm[0] / (double)W_ELEMS + 1e-6;
        *thr = (float)(0.5 * gamma);   // Wq nonzero iff |W| > 0.5*gamma
    }
}

// ---------------- Pass 2: quantize W -> ternary int8 ----------------
__global__ __launch_bounds__(256) void quantw_kernel(const float4* __restrict__ W4,
                                                     char4* __restrict__ wq4,
                                                     const float* __restrict__ thrp) {
    float thr = *thrp;
    long base = (long)blockIdx.x * 2048 + threadIdx.x;   // 8192 blocks, 8 f4/thread
#pragma unroll
    for (int j = 0; j < 8; ++j) {
        long idx = base + (long)j * 256;
        float4 v = W4[idx];
        char4 q;
        q.x = (fabsf(v.x) > thr) ? ((v.x > 0.f) ? 1 : -1) : 0;
        q.y = (fabsf(v.y) > thr) ? ((v.y > 0.f) ? 1 : -1) : 0;
        q.z = (fabsf(v.z) > thr) ? ((v.z > 0.f) ? 1 : -1) : 0;
        q.w = (fabsf(v.w) > thr) ? ((v.w > 0.f) ? 1 : -1) : 0;
        wq4[idx] = q;
    }
}

// ---------------- Pass 3: binarize x -> sign int8 ----------------
__global__ __launch_bounds__(256) void quantx_kernel(const float4* __restrict__ X4,
                                                     char4* __restrict__ xq4) {
    long base = (long)blockIdx.x * 2048 + threadIdx.x;   // 4096 blocks, 8 f4/thread
#pragma unroll
    for (int j = 0; j < 8; ++j) {
        long idx = base + (long)j * 256;
        float4 v = X4[idx];
        char4 q;
        q.x = (v.x > 0.f) ? 1 : ((v.x < 0.f) ? -1 : 0);
        q.y = (v.y > 0.f) ? 1 : ((v.y < 0.f) ? -1 : 0);
        q.z = (v.z > 0.f) ? 1 : ((v.z < 0.f) ? -1 : 0);
        q.w = (v.w > 0.f) ? 1 : ((v.w < 0.f) ? -1 : 0);
        xq4[idx] = q;
    }
}

// ---------------- Pass 4: i8 GEMM, m97 128^2-tile structure ----------------
// A = xq [M][K] i8 (K-major), B = wq [N][K] i8 (K-major, i.e. B^T input),
// C[m][n] = sum_k A[m][k]*B[n][k].  BM=BN=128, BK=64, 256 thr = 4 waves,
// wave (wr,wc) owns a 64x64 subtile = 4x4 fragments of 16x16x64 i8 MFMA.
__global__ __launch_bounds__(256) void gemm_i8_kernel(const int8_t* __restrict__ A,
                                                      const int8_t* __restrict__ B,
                                                      float* __restrict__ C) {
    __shared__ int8_t sA[128 * 64];   // 8 KiB
    __shared__ int8_t sB[128 * 64];   // 8 KiB

    const int t = threadIdx.x;
    const int l = t & 63;
    const int w = t >> 6;
    const int wr = w >> 1;            // 0..1
    const int wc = w & 1;             // 0..1

    // Bijective XCD swizzle: 8192 wgs, 8192 % 8 == 0.
    int wg = blockIdx.x;
    int sw = (wg & 7) * 1024 + (wg >> 3);
    int bm = sw & 63;                 // 64 M-tiles
    int bn = sw >> 6;                 // 128 N-tiles
    const long m0 = (long)bm * 128;
    const long n0 = (long)bn * 128;

    v4i acc[4][4] = {};

    const int r0 = l & 15;            // fragment row within 16
    const int kb = (l >> 4) * 16;     // k-byte offset within BK=64

    // Staging: tile is 128 rows x 64 B = 512 chunks of 16 B; thread t takes
    // chunks {t, 256+t}; within a wave lds dests are base + lane*16 (linear).
    const int c0 = t;
    const int c1 = 256 + t;
    const int rowA0 = c0 >> 2, colb0 = (c0 & 3) * 16;
    const int rowA1 = c1 >> 2, colb1 = (c1 & 3) * 16;

    for (int k0 = 0; k0 < Kx; k0 += 64) {
        const int8_t* gA0 = A + (m0 + rowA0) * Kx + k0 + colb0;
        const int8_t* gA1 = A + (m0 + rowA1) * Kx + k0 + colb1;
        const int8_t* gB0 = B + (n0 + rowA0) * Kx + k0 + colb0;
        const int8_t* gB1 = B + (n0 + rowA1) * Kx + k0 + colb1;
        __builtin_amdgcn_global_load_lds(GLOBAL_AS(gA0), LDS_AS(sA + c0 * 16), 16, 0, 0);
        __builtin_amdgcn_global_load_lds(GLOBAL_AS(gA1), LDS_AS(sA + c1 * 16), 16, 0, 0);
        __builtin_amdgcn_global_load_lds(GLOBAL_AS(gB0), LDS_AS(sB + c0 * 16), 16, 0, 0);
        __builtin_amdgcn_global_load_lds(GLOBAL_AS(gB1), LDS_AS(sB + c1 * 16), 16, 0, 0);
        __syncthreads();

        v4i af[4], bf[4];
#pragma unroll
        for (int m = 0; m < 4; ++m)
            af[m] = *(const v4i*)&sA[(wr * 64 + m * 16 + r0) * 64 + kb];
#pragma unroll
        for (int n = 0; n < 4; ++n)
            bf[n] = *(const v4i*)&sB[(wc * 64 + n * 16 + r0) * 64 + kb];
#pragma unroll
        for (int m = 0; m < 4; ++m)
#pragma unroll
            for (int n = 0; n < 4; ++n)
                acc[m][n] = __builtin_amdgcn_mfma_i32_16x16x64_i8(af[m], bf[n], acc[m][n], 0, 0, 0);
        __syncthreads();
    }

    // Epilogue: C/D 16x16 layout col = lane&15, row = (lane>>4)*4 + reg.
    const int cr = (l >> 4) * 4;
    const int cc = l & 15;
#pragma unroll
    for (int m = 0; m < 4; ++m) {
        long grow = m0 + wr * 64 + m * 16 + cr;
#pragma unroll
        for (int n = 0; n < 4; ++n) {
            long gcol = n0 + wc * 64 + n * 16 + cc;
#pragma unroll
            for (int r = 0; r < 4; ++r)
                C[(grow + r) * Nx + gcol] = (float)acc[m][n][r];
        }
    }
}

extern "C" void kernel_launch(void* const* d_in, const int* in_sizes, int n_in,
                              void* d_out, int out_size, void* d_ws, size_t ws_size,
                              hipStream_t stream) {
    const float* x = (const float*)d_in[0];        // 33554432 f32
    const float* weight = (const float*)d_in[1];   // 67108864 f32
    float* out = (float*)d_out;                    // 134217728 f32

    // Workspace layout (all 256B-aligned): xq 32MB | wq 64MB | partials 16KB | thr
    int8_t* xq = (int8_t*)d_ws;
    int8_t* wq = xq + X_ELEMS;
    double* partials = (double*)((char*)d_ws + X_ELEMS + W_ELEMS);
    float* thr = (float*)((char*)d_ws + X_ELEMS + W_ELEMS + 2048 * sizeof(double));

    absum_kernel<<<2048, 256, 0, stream>>>((const float4*)weight, partials);
    finalize_kernel<<<1, 256, 0, stream>>>(partials, thr);
    quantw_kernel<<<8192, 256, 0, stream>>>((const float4*)weight, (char4*)wq, thr);
    quantx_kernel<<<4096, 256, 0, stream>>>((const float4*)x, (char4*)xq);
    gemm_i8_kernel<<<8192, 256, 0, stream>>>(xq, wq, out);
}

// Round 2
// 824.416 us; speedup vs baseline: 1.1466x; 1.1466x over previous
//
#include <hip/hip_runtime.h>
#include <hip/hip_bf16.h>
#include <cstdint>

constexpr int Mx = 8192;
constexpr int Kx = 4096;
constexpr int Nx = 16384;
constexpr long W_ELEMS = (long)Nx * Kx;      // 67108864
constexpr long X_ELEMS = (long)Mx * Kx;      // 33554432

typedef int v4i __attribute__((ext_vector_type(4)));

#define GLOBAL_AS(p) ((const __attribute__((address_space(1))) void*)(p))
#define LDS_AS(p)    ((__attribute__((address_space(3))) void*)(p))

template <int P> struct IC { static constexpr int value = P; };

// ---------------- Pass 1: sum |W| (deterministic two-level tree) ----------------
__global__ __launch_bounds__(256) void absum_kernel(const float4* __restrict__ W4,
                                                    double* __restrict__ partials) {
    int t = threadIdx.x;
    long base = (long)blockIdx.x * 8192;
    double s = 0.0;
#pragma unroll 4
    for (int i = 0; i < 32; ++i) {
        float4 v = W4[base + (long)i * 256 + t];
        s += (double)fabsf(v.x) + (double)fabsf(v.y) +
             (double)fabsf(v.z) + (double)fabsf(v.w);
    }
    __shared__ double sm[256];
    sm[t] = s;
    __syncthreads();
    for (int off = 128; off > 0; off >>= 1) {
        if (t < off) sm[t] += sm[t + off];
        __syncthreads();
    }
    if (t == 0) partials[blockIdx.x] = sm[0];
}

__global__ __launch_bounds__(256) void finalize_kernel(const double* __restrict__ partials,
                                                       float* __restrict__ thr) {
    int t = threadIdx.x;
    double s = 0.0;
#pragma unroll
    for (int i = 0; i < 8; ++i) s += partials[(long)i * 256 + t];
    __shared__ double sm[256];
    sm[t] = s;
    __syncthreads();
    for (int off = 128; off > 0; off >>= 1) {
        if (t < off) sm[t] += sm[t + off];
        __syncthreads();
    }
    if (t == 0) {
        double gamma = sm[0] / (double)W_ELEMS + 1e-6;
        *thr = (float)(0.5 * gamma);
    }
}

// ---------------- Pass 2: quantize W -> ternary int8 ----------------
__global__ __launch_bounds__(256) void quantw_kernel(const float4* __restrict__ W4,
                                                     char4* __restrict__ wq4,
                                                     const float* __restrict__ thrp) {
    float thr = *thrp;
    long base = (long)blockIdx.x * 2048 + threadIdx.x;
#pragma unroll
    for (int j = 0; j < 8; ++j) {
        long idx = base + (long)j * 256;
        float4 v = W4[idx];
        char4 q;
        q.x = (fabsf(v.x) > thr) ? ((v.x > 0.f) ? 1 : -1) : 0;
        q.y = (fabsf(v.y) > thr) ? ((v.y > 0.f) ? 1 : -1) : 0;
        q.z = (fabsf(v.z) > thr) ? ((v.z > 0.f) ? 1 : -1) : 0;
        q.w = (fabsf(v.w) > thr) ? ((v.w > 0.f) ? 1 : -1) : 0;
        wq4[idx] = q;
    }
}

// ---------------- Pass 3: binarize x -> sign int8 ----------------
__global__ __launch_bounds__(256) void quantx_kernel(const float4* __restrict__ X4,
                                                     char4* __restrict__ xq4) {
    long base = (long)blockIdx.x * 2048 + threadIdx.x;
#pragma unroll
    for (int j = 0; j < 8; ++j) {
        long idx = base + (long)j * 256;
        float4 v = X4[idx];
        char4 q;
        q.x = (v.x > 0.f) ? 1 : ((v.x < 0.f) ? -1 : 0);
        q.y = (v.y > 0.f) ? 1 : ((v.y < 0.f) ? -1 : 0);
        q.z = (v.z > 0.f) ? 1 : ((v.z < 0.f) ? -1 : 0);
        q.w = (v.w > 0.f) ? 1 : ((v.w < 0.f) ? -1 : 0);
        xq4[idx] = q;
    }
}

// ---------------- Pass 4: i8 GEMM, 256^2 tile, 8-phase counted-vmcnt schedule ----
// A = xq [M][K], B = wq [N][K] (K-major).  BM=BN=256, BK=128 i8.
// 512 thr = 8 waves (2M x 4N); per-wave output 128x64.
// Stage unit = 256 rows x 64B (one k-half of A or B) = 16 KB = 1 LDS slot.
// Unit stream S(j): tile=j>>2, u=j&3: {A,k0},{B,k0},{A,k1},{B,k1}.
// Slot ring = 8 slots.  Issue lead = 6 units (unit S(j) consumed at phases
// {j,j+1}; slot of S(j-8) freed at phase j-7+... last read j+1-8+... safe).
// One vmcnt(4) per K-tile boundary (vmcnt(0) only before the last tile).
// LDS swizzle: off = r*64 + (c16 ^ (((r>>1)&3)<<4)) applied via pre-swizzled
// global source (gload_lds dest stays linear) + same XOR on ds_read.
__global__ __launch_bounds__(512, 1) void gemm_i8_8ph(const int8_t* __restrict__ A,
                                                      const int8_t* __restrict__ B,
                                                      float* __restrict__ C) {
    __shared__ __align__(16) int8_t smem[8 * 16384];   // 128 KiB

    const int t = threadIdx.x;
    const int l = t & 63;
    const int wid = t >> 6;
    const int wm = wid >> 2;          // 0..1
    const int wn = wid & 3;           // 0..3
    const int g = l >> 4;             // k-chunk within fragment
    const int i = l & 15;             // row within fragment

    // Bijective XCD swizzle: 2048 wgs % 8 == 0.
    int wg = blockIdx.x;
    int sw = (wg & 7) * 256 + (wg >> 3);
    int bm = sw & 31;                 // 32 M-tiles
    int bn = sw >> 5;                 // 64 N-tiles
    const long m0 = (long)bm * 256;
    const long n0 = (long)bn * 256;

    // Stage source bases (chunks c0 = t, c1 = t+512 of the 1024-chunk unit).
    // Pre-swizzled source: phys chunk (r, cp) holds global k-chunk cp ^ ((r>>1)&3).
    const int c0 = t, c1 = t + 512;
    const int r0s = c0 >> 2, r1s = c1 >> 2;
    const int kb0 = (((c0 & 3) ^ ((r0s >> 1) & 3)) << 4);
    const int kb1 = (((c1 & 3) ^ ((r1s >> 1) & 3)) << 4);
    const int8_t* gA0 = A + (m0 + r0s) * (long)Kx + kb0;
    const int8_t* gA1 = A + (m0 + r1s) * (long)Kx + kb1;
    const int8_t* gB0 = B + (n0 + r0s) * (long)Kx + kb0;
    const int8_t* gB1 = B + (n0 + r1s) * (long)Kx + kb1;
    const int lo0 = c0 * 16, lo1 = c1 * 16;

    // Per-thread ds_read offsets within a slot (swizzled).
    int offA[2][4], offB[4];
#pragma unroll
    for (int h = 0; h < 2; ++h)
#pragma unroll
        for (int mf = 0; mf < 4; ++mf) {
            int r = wm * 128 + h * 64 + mf * 16 + i;
            offA[h][mf] = r * 64 + ((g * 16) ^ (((r >> 1) & 3) << 4));
        }
#pragma unroll
    for (int nf = 0; nf < 4; ++nf) {
        int r = wn * 64 + nf * 16 + i;
        offB[nf] = r * 64 + ((g * 16) ^ (((r >> 1) & 3) << 4));
    }

    v4i acc[8][4] = {};

    // Prologue: issue units S(0..5), wait to 2 units in flight, publish.
#pragma unroll
    for (int j = 0; j < 6; ++j) {
        int tj = j >> 2, u = j & 3, slot = j & 7;
        long koff = (long)tj * 128 + (long)(u >> 1) * 64;
        if (u & 1) {
            __builtin_amdgcn_global_load_lds(GLOBAL_AS(gB0 + koff), LDS_AS(smem + slot * 16384 + lo0), 16, 0, 0);
            __builtin_amdgcn_global_load_lds(GLOBAL_AS(gB1 + koff), LDS_AS(smem + slot * 16384 + lo1), 16, 0, 0);
        } else {
            __builtin_amdgcn_global_load_lds(GLOBAL_AS(gA0 + koff), LDS_AS(smem + slot * 16384 + lo0), 16, 0, 0);
            __builtin_amdgcn_global_load_lds(GLOBAL_AS(gA1 + koff), LDS_AS(smem + slot * 16384 + lo1), 16, 0, 0);
        }
    }
    asm volatile("s_waitcnt vmcnt(4)" ::: "memory");
    __builtin_amdgcn_s_barrier();

#pragma unroll 2
    for (int tau = 0; tau < 32; ++tau) {
        const int sb = (tau & 1) * 4;
        v4i bf[4];

        auto phase = [&](auto pc) {
            constexpr int P = decltype(pc)::value;
            constexpr int q = P >> 1;
            constexpr int h = P & 1;
            const int slA = sb + 2 * q;
            v4i af[4];
#pragma unroll
            for (int mf = 0; mf < 4; ++mf)
                af[mf] = *(const v4i*)(smem + slA * 16384 + offA[h][mf]);
            if constexpr (h == 0) {
#pragma unroll
                for (int nf = 0; nf < 4; ++nf)
                    bf[nf] = *(const v4i*)(smem + (slA + 1) * 16384 + offB[nf]);
            }
            // Stage S(4*tau + P + 6): overwrites slot of S(phi-2), already consumed.
            {
                int j = 4 * tau + P + 6;
                if (j < 128) {
                    int tj = j >> 2;
                    int slot = j & 7;
                    constexpr int u = (P + 2) & 3;
                    constexpr long qoff = (long)(u >> 1) * 64;
                    long koff = (long)tj * 128 + qoff;
                    const int8_t* s0 = (u & 1) ? gB0 : gA0;
                    const int8_t* s1 = (u & 1) ? gB1 : gA1;
                    __builtin_amdgcn_global_load_lds(GLOBAL_AS(s0 + koff), LDS_AS(smem + slot * 16384 + lo0), 16, 0, 0);
                    __builtin_amdgcn_global_load_lds(GLOBAL_AS(s1 + koff), LDS_AS(smem + slot * 16384 + lo1), 16, 0, 0);
                }
            }
            __builtin_amdgcn_s_barrier();
            asm volatile("s_waitcnt lgkmcnt(0)" ::: "memory");
            __builtin_amdgcn_sched_barrier(0);
            __builtin_amdgcn_s_setprio(1);
#pragma unroll
            for (int mf = 0; mf < 4; ++mf)
#pragma unroll
                for (int nf = 0; nf < 4; ++nf)
                    acc[h * 4 + mf][nf] = __builtin_amdgcn_mfma_i32_16x16x64_i8(
                        af[mf], bf[nf], acc[h * 4 + mf][nf], 0, 0, 0);
            __builtin_amdgcn_s_setprio(0);
            if constexpr (P == 3) {
                if (tau == 30) asm volatile("s_waitcnt vmcnt(0)" ::: "memory");
                else if (tau < 30) asm volatile("s_waitcnt vmcnt(4)" ::: "memory");
            }
            __builtin_amdgcn_s_barrier();
        };

        phase(IC<0>{});
        phase(IC<1>{});
        phase(IC<2>{});
        phase(IC<3>{});
    }

    // Epilogue: C/D layout col = lane&15, row = (lane>>4)*4 + reg.
    const int cr = g * 4;
    const int cc = i;
#pragma unroll
    for (int m = 0; m < 8; ++m) {
        long grow = m0 + wm * 128 + m * 16 + cr;
#pragma unroll
        for (int nf = 0; nf < 4; ++nf) {
            long gcol = n0 + wn * 64 + nf * 16 + cc;
#pragma unroll
            for (int r = 0; r < 4; ++r)
                C[(grow + r) * Nx + gcol] = (float)acc[m][nf][r];
        }
    }
}

extern "C" void kernel_launch(void* const* d_in, const int* in_sizes, int n_in,
                              void* d_out, int out_size, void* d_ws, size_t ws_size,
                              hipStream_t stream) {
    const float* x = (const float*)d_in[0];
    const float* weight = (const float*)d_in[1];
    float* out = (float*)d_out;

    int8_t* xq = (int8_t*)d_ws;
    int8_t* wq = xq + X_ELEMS;
    double* partials = (double*)((char*)d_ws + X_ELEMS + W_ELEMS);
    float* thr = (float*)((char*)d_ws + X_ELEMS + W_ELEMS + 2048 * sizeof(double));

    absum_kernel<<<2048, 256, 0, stream>>>((const float4*)weight, partials);
    finalize_kernel<<<1, 256, 0, stream>>>(partials, thr);
    quantw_kernel<<<8192, 256, 0, stream>>>((const float4*)weight, (char4*)wq, thr);
    quantx_kernel<<<4096, 256, 0, stream>>>((const float4*)x, (char4*)xq);
    gemm_i8_8ph<<<2048, 512, 0, stream>>>(xq, wq, out);
}